// Round 4
// baseline (137.840 us; speedup 1.0000x reference)
//
#include <hip/hip_runtime.h>

// Holt-Winters triple exponential smoothing, 32768 windows x 511 steps.
// One wave (64 threads) per block; each thread owns one window.
// x is staged through LDS in 96-step superblocks with a COALESCED mapping
// (the naive row-per-thread read pattern is 64-way address-divergent).
// Seasonal state S[24] stays in registers: every index is compile-time
// constant because 96 % 24 == 0 (each superblock starts at si == 4).

#define F_WINDOW 512
#define SEASONP  24
#define HORIZON  12
#define ROWS     64      // windows per block (= wave size)
#define LSTRIDE  97      // LDS row stride in floats (97: bank = (t+k)%32, 2-way = free)
#define SB_F4    24      // float4 per row per superblock (96 floats = 4*24 steps)

// One smoothing step. si MUST be a compile-time constant after unroll.
// u-form for bn: bn = (1-ab)*b - ab*L + ab*(xi-Sv)  (no dependence on Ln ->
// critical path per step is 2 dependent VALU ops for both L and b chains).
#define HW_STEP(xi, si) do {                       \
    const float Sv  = S[si];                       \
    const float d   = (xi) - Sv;                   \
    const float ad  = alpha * d;        /* a*d  */ \
    const float s_  = L + b;                       \
    const float Ln  = fmaf(oma, s_, ad);           \
    const float abd = beta * ad;        /* ab*d */ \
    const float tb  = fmaf(omab, b, abd);          \
    const float bn  = fmaf(ab, -L, tb);            \
    const float e   = (xi) - Ln;                   \
    const float gs  = omg * Sv;                    \
    S[si] = fmaf(gamma, e, gs);                    \
    L = Ln; b = bn;                                \
} while (0)

// 24 steps whose global step index i satisfies i % 24 == 4 at entry.
#define HW_LDS24(row, B) do {                                                                \
    HW_STEP((row)[(B)+ 0], 4); HW_STEP((row)[(B)+ 1], 5); HW_STEP((row)[(B)+ 2], 6);        \
    HW_STEP((row)[(B)+ 3], 7); HW_STEP((row)[(B)+ 4], 8); HW_STEP((row)[(B)+ 5], 9);        \
    HW_STEP((row)[(B)+ 6],10); HW_STEP((row)[(B)+ 7],11); HW_STEP((row)[(B)+ 8],12);        \
    HW_STEP((row)[(B)+ 9],13); HW_STEP((row)[(B)+10],14); HW_STEP((row)[(B)+11],15);        \
    HW_STEP((row)[(B)+12],16); HW_STEP((row)[(B)+13],17); HW_STEP((row)[(B)+14],18);        \
    HW_STEP((row)[(B)+15],19); HW_STEP((row)[(B)+16],20); HW_STEP((row)[(B)+17],21);        \
    HW_STEP((row)[(B)+18],22); HW_STEP((row)[(B)+19],23); HW_STEP((row)[(B)+20], 0);        \
    HW_STEP((row)[(B)+21], 1); HW_STEP((row)[(B)+22], 2); HW_STEP((row)[(B)+23], 3);        \
} while (0)

// Same 24-step pattern from six float4 (for the direct-loaded tail).
#define HW_BLOCK24(v0, v1, v2, v3, v4, v5) do {                                  \
    HW_STEP(v0.x,  4); HW_STEP(v0.y,  5); HW_STEP(v0.z,  6); HW_STEP(v0.w,  7); \
    HW_STEP(v1.x,  8); HW_STEP(v1.y,  9); HW_STEP(v1.z, 10); HW_STEP(v1.w, 11); \
    HW_STEP(v2.x, 12); HW_STEP(v2.y, 13); HW_STEP(v2.z, 14); HW_STEP(v2.w, 15); \
    HW_STEP(v3.x, 16); HW_STEP(v3.y, 17); HW_STEP(v3.z, 18); HW_STEP(v3.w, 19); \
    HW_STEP(v4.x, 20); HW_STEP(v4.y, 21); HW_STEP(v4.z, 22); HW_STEP(v4.w, 23); \
    HW_STEP(v5.x,  0); HW_STEP(v5.y,  1); HW_STEP(v5.z,  2); HW_STEP(v5.w,  3); \
} while (0)

// Issue the 24 coalesced float4 loads for superblock sb into stg[] (in flight).
#define ISSUE_LOADS(sb) do {                                          \
    const float* gp = xblk + 4 + 96 * (sb);                           \
    _Pragma("unroll")                                                 \
    for (int j = 0; j < SB_F4; ++j)                                   \
        stg[j] = *(const float4*)(gp + goff[j]);                      \
} while (0)

// Scatter stg[] into an LDS buffer (4B-granular; stride 97 kills conflicts).
#define WRITE_LDS(buf) do {                                           \
    _Pragma("unroll")                                                 \
    for (int j = 0; j < SB_F4; ++j) {                                 \
        float* p = (buf) + loff[j];                                   \
        p[0] = stg[j].x; p[1] = stg[j].y;                             \
        p[2] = stg[j].z; p[3] = stg[j].w;                             \
    }                                                                 \
} while (0)

__global__ __launch_bounds__(64) void holtwinter_kernel(
    const float* __restrict__ x,
    const float* __restrict__ y,
    const float* __restrict__ init_L,
    const float* __restrict__ init_b,
    const float* __restrict__ init_S,
    const float* __restrict__ p_alpha,
    const float* __restrict__ p_beta,
    const float* __restrict__ p_gamma,
    float* __restrict__ out)
{
    __shared__ float lds[2][ROWS * LSTRIDE];   // 2 x 24.8 KB

    const int t = threadIdx.x;
    const int n = blockIdx.x * ROWS + t;

    const float alpha = p_alpha[0];
    const float beta  = p_beta[0];
    const float gamma = p_gamma[0];
    const float oma   = 1.0f - alpha;
    const float ab    = alpha * beta;
    const float omab  = 1.0f - ab;
    const float omg   = 1.0f - gamma;

    const float* __restrict__ xblk = x + (size_t)blockIdx.x * ROWS * F_WINDOW;
    const float* __restrict__ xr   = x + (size_t)n * F_WINDOW;

    // Coalesced staging map: flat float4 index g = j*64 + t -> row r = g/24,
    // f4-col c = g%24. Per instruction: ~3 contiguous 384B row segments.
    int goff[SB_F4], loff[SB_F4];
    {
        int r = t / 24, c = t - (t / 24) * 24;
        #pragma unroll
        for (int j = 0; j < SB_F4; ++j) {
            goff[j] = r * F_WINDOW + 4 * c;
            loff[j] = r * LSTRIDE  + 4 * c;
            r += 2; c += 16;
            if (c >= 24) { c -= 24; r += 1; }
        }
    }

    // Seasonal state in registers (float4 row: 96B-aligned since 96 = 6*16).
    float S[SEASONP];
    {
        const float4* iS4 = (const float4*)(init_S + (size_t)n * SEASONP);
        float4 s0 = iS4[0], s1 = iS4[1], s2 = iS4[2];
        float4 s3 = iS4[3], s4 = iS4[4], s5 = iS4[5];
        S[0]=s0.x;  S[1]=s0.y;  S[2]=s0.z;  S[3]=s0.w;
        S[4]=s1.x;  S[5]=s1.y;  S[6]=s1.z;  S[7]=s1.w;
        S[8]=s2.x;  S[9]=s2.y;  S[10]=s2.z; S[11]=s2.w;
        S[12]=s3.x; S[13]=s3.y; S[14]=s3.z; S[15]=s3.w;
        S[16]=s4.x; S[17]=s4.y; S[18]=s4.z; S[19]=s4.w;
        S[20]=s5.x; S[21]=s5.y; S[22]=s5.z; S[23]=s5.w;
    }

    float L = init_L[n];
    float b = init_b[n];

    float4 stg[SB_F4];
    float* bcur = lds[0];
    float* bnxt = lds[1];

    // Stage superblock 0 (steps i = 4..99).
    ISSUE_LOADS(0);
    WRITE_LDS(bcur);
    __syncthreads();           // drain lgkm before cross-lane reads

    // Prologue: i = 1..3 (si = 1,2,3); one divergent float4, hidden by stage.
    {
        const float4 v = *(const float4*)(xr);   // x[0..3]; x[0] unused
        HW_STEP(v.y, 1);
        HW_STEP(v.z, 2);
        HW_STEP(v.w, 3);
    }

    // Superblocks 0..3: compute s from LDS while s+1's loads are in flight.
    #pragma unroll 1
    for (int s = 0; s < 4; ++s) {
        ISSUE_LOADS(s + 1);                       // overlap with compute below
        const float* row = bcur + t * LSTRIDE;
        HW_LDS24(row,  0);
        HW_LDS24(row, 24);
        HW_LDS24(row, 48);
        HW_LDS24(row, 72);
        WRITE_LDS(bnxt);                          // vmcnt waits inserted here
        __syncthreads();                          // writes visible to all lanes
        float* tmp = bcur; bcur = bnxt; bnxt = tmp;
    }

    // Superblock 4 (i = 388..483): compute only.
    {
        const float* row = bcur + t * LSTRIDE;
        HW_LDS24(row,  0);
        HW_LDS24(row, 24);
        HW_LDS24(row, 48);
        HW_LDS24(row, 72);
    }

    // Tail: i = 484..511 (484 % 24 == 4). 7 direct float4 (divergent but tiny).
    {
        const float4 v0 = *(const float4*)(xr + 484);
        const float4 v1 = *(const float4*)(xr + 488);
        const float4 v2 = *(const float4*)(xr + 492);
        const float4 v3 = *(const float4*)(xr + 496);
        const float4 v4 = *(const float4*)(xr + 500);
        const float4 v5 = *(const float4*)(xr + 504);
        const float4 v6 = *(const float4*)(xr + 508);
        HW_BLOCK24(v0, v1, v2, v3, v4, v5);       // i = 484..507
        HW_STEP(v6.x, 4); HW_STEP(v6.y, 5);       // i = 508..511
        HW_STEP(v6.z, 6); HW_STEP(v6.w, 7);
    }

    // Forecast & loss term. s_idx = (511 + 12) % 24 = 19.
    const float f    = fmaf((float)HORIZON, b, L) * S[19];
    const float diff = f - y[n];
    float val = diff * diff;

    // Wave (=block) reduction, one atomic per block.
    #pragma unroll
    for (int off = 32; off > 0; off >>= 1)
        val += __shfl_down(val, off);
    if (t == 0)
        atomicAdd(out, val);
}

extern "C" void kernel_launch(void* const* d_in, const int* in_sizes, int n_in,
                              void* d_out, int out_size, void* d_ws, size_t ws_size,
                              hipStream_t stream) {
    const float* x      = (const float*)d_in[0];
    const float* y      = (const float*)d_in[1];
    const float* init_L = (const float*)d_in[2];
    const float* init_b = (const float*)d_in[3];
    const float* init_S = (const float*)d_in[4];
    const float* alpha  = (const float*)d_in[5];
    const float* beta   = (const float*)d_in[6];
    const float* gamma  = (const float*)d_in[7];
    float* out = (float*)d_out;

    const int N = in_sizes[1];          // number of windows (32768)

    hipMemsetAsync(d_out, 0, (size_t)out_size * sizeof(float), stream);  // 0xAA-poisoned
    holtwinter_kernel<<<N / ROWS, ROWS, 0, stream>>>(
        x, y, init_L, init_b, init_S, alpha, beta, gamma, out);
}

// Round 8
// 121.524 us; speedup vs baseline: 1.1343x; 1.1343x over previous
//
#include <hip/hip_runtime.h>

// Holt-Winters triple exponential smoothing, 32768 windows x 511 steps.
// One thread per window (512 waves total -> ~0.5 waves/SIMD: NO TLP exists,
// so all latency must be hidden by ILP inside the wave). Strategy: direct
// global float4 loads with an explicit 3-buffer, 2-block-deep register
// prefetch pipeline (named buffers A/B/C, period-3 loop -> no rotation).
// Seasonal state S[24] lives in registers: 24-step blocks keep every S
// index a compile-time constant. R4 post-mortem: LDS staging regressed
// (49us, VALUBusy 8%) because compiler issued ds_reads just-in-time and
// sank the staging loads; this version forces load issue distance in source.

#define F_WINDOW 512
#define SEASONP  24
#define HORIZON  12

// One smoothing step. si MUST be a compile-time constant.
// u-form for bn: bn = (1-ab)*b - ab*L + ab*(xi-Sv)  (no dependence on Ln ->
// L and b chains are independent, 2 dependent FMAs each per step).
#define HW_STEP(xi, si) do {                       \
    const float Sv  = S[si];                       \
    const float d   = (xi) - Sv;                   \
    const float ad  = alpha * d;        /* a*d  */ \
    const float s_  = L + b;                       \
    const float Ln  = fmaf(oma, s_, ad);           \
    const float abd = beta * ad;        /* ab*d */ \
    const float tb  = fmaf(omab, b, abd);          \
    const float bn  = fmaf(ab, -L, tb);            \
    const float e   = (xi) - Ln;                   \
    const float gs  = omg * Sv;                    \
    S[si] = fmaf(gamma, e, gs);                    \
    L = Ln; b = bn;                                \
} while (0)

// 24 steps from six float4; entry step index i satisfies i % 24 == 4.
#define HW_BLOCK24(v0, v1, v2, v3, v4, v5) do {                                  \
    HW_STEP(v0.x,  4); HW_STEP(v0.y,  5); HW_STEP(v0.z,  6); HW_STEP(v0.w,  7); \
    HW_STEP(v1.x,  8); HW_STEP(v1.y,  9); HW_STEP(v1.z, 10); HW_STEP(v1.w, 11); \
    HW_STEP(v2.x, 12); HW_STEP(v2.y, 13); HW_STEP(v2.z, 14); HW_STEP(v2.w, 15); \
    HW_STEP(v3.x, 16); HW_STEP(v3.y, 17); HW_STEP(v3.z, 18); HW_STEP(v3.w, 19); \
    HW_STEP(v4.x, 20); HW_STEP(v4.y, 21); HW_STEP(v4.z, 22); HW_STEP(v4.w, 23); \
    HW_STEP(v5.x,  0); HW_STEP(v5.y,  1); HW_STEP(v5.z,  2); HW_STEP(v5.w,  3); \
} while (0)

// Issue six float4 loads into named buffer Bn0..Bn5 (stays in VGPRs).
#define LOAD6(Bn, base) do {                                \
    Bn##0 = *(const float4*)((base) +  0);                  \
    Bn##1 = *(const float4*)((base) +  4);                  \
    Bn##2 = *(const float4*)((base) +  8);                  \
    Bn##3 = *(const float4*)((base) + 12);                  \
    Bn##4 = *(const float4*)((base) + 16);                  \
    Bn##5 = *(const float4*)((base) + 20);                  \
} while (0)

__global__ __launch_bounds__(64) void holtwinter_kernel(
    const float* __restrict__ x,
    const float* __restrict__ y,
    const float* __restrict__ init_L,
    const float* __restrict__ init_b,
    const float* __restrict__ init_S,
    const float* __restrict__ p_alpha,
    const float* __restrict__ p_beta,
    const float* __restrict__ p_gamma,
    float* __restrict__ out)
{
    const int n = blockIdx.x * 64 + threadIdx.x;

    // Uniform scalars -> scalarized loads.
    const float alpha = p_alpha[0];
    const float beta  = p_beta[0];
    const float gamma = p_gamma[0];
    const float oma   = 1.0f - alpha;
    const float ab    = alpha * beta;
    const float omab  = 1.0f - ab;
    const float omg   = 1.0f - gamma;

    const float* __restrict__ xr = x + (size_t)n * F_WINDOW;

    // ---- issue ALL front-of-pipe loads before any compute ----
    float4 A0, A1, A2, A3, A4, A5;      // block m   (being computed)
    float4 B0, B1, B2, B3, B4, B5;      // block m+1 (in flight / ready)
    float4 C0, C1, C2, C3, C4, C5;      // block m+2 (in flight)

    LOAD6(A, xr + 4);                    // block 0: i = 4..27
    LOAD6(B, xr + 4 + 24);               // block 1: i = 28..51
    const float4 P = *(const float4*)(xr);        // i = 0..3 (x[0] unused)
    const float4 T = *(const float4*)(xr + 508);  // tail i = 508..511
    const float  yv = y[n];
    const float  L0 = init_L[n];
    const float  b0 = init_b[n];

    // Seasonal state into registers (row is 96B-aligned: 96 = 6*16).
    float S[SEASONP];
    {
        const float4* iS4 = (const float4*)(init_S + (size_t)n * SEASONP);
        float4 s0 = iS4[0], s1 = iS4[1], s2 = iS4[2];
        float4 s3 = iS4[3], s4 = iS4[4], s5 = iS4[5];
        S[0]=s0.x;  S[1]=s0.y;  S[2]=s0.z;  S[3]=s0.w;
        S[4]=s1.x;  S[5]=s1.y;  S[6]=s1.z;  S[7]=s1.w;
        S[8]=s2.x;  S[9]=s2.y;  S[10]=s2.z; S[11]=s2.w;
        S[12]=s3.x; S[13]=s3.y; S[14]=s3.z; S[15]=s3.w;
        S[16]=s4.x; S[17]=s4.y; S[18]=s4.z; S[19]=s4.w;
        S[20]=s5.x; S[21]=s5.y; S[22]=s5.z; S[23]=s5.w;
    }

    float L = L0;
    float b = b0;

    // Prologue steps i = 1..3 (si = 1,2,3).
    HW_STEP(P.y, 1);
    HW_STEP(P.z, 2);
    HW_STEP(P.w, 3);

    // 21 blocks of 24 steps (i = 4..507) in 7 period-3 pipeline turns.
    // Iteration k computes blocks 3k, 3k+1, 3k+2 and refills two blocks
    // ahead: while block m runs, loads for m+1 and m+2 are in flight.
    #pragma unroll 1
    for (int k = 0; k < 6; ++k) {
        const float* base = xr + 4 + 72 * k;
        LOAD6(C, base + 48);                       // block 3k+2
        HW_BLOCK24(A0, A1, A2, A3, A4, A5);        // block 3k
        LOAD6(A, base + 72);                       // block 3k+3
        HW_BLOCK24(B0, B1, B2, B3, B4, B5);        // block 3k+1
        LOAD6(B, base + 96);                       // block 3k+4
        HW_BLOCK24(C0, C1, C2, C3, C4, C5);        // block 3k+2
    }
    // Last turn (k = 6): blocks 18, 19, 20 — no refills past the end.
    LOAD6(C, xr + 4 + 24 * 20);                    // block 20
    HW_BLOCK24(A0, A1, A2, A3, A4, A5);            // block 18
    HW_BLOCK24(B0, B1, B2, B3, B4, B5);            // block 19
    HW_BLOCK24(C0, C1, C2, C3, C4, C5);            // block 20 (i = 484..507)

    // Tail steps i = 508..511 (si = 4..7), loaded at kernel entry.
    HW_STEP(T.x, 4); HW_STEP(T.y, 5); HW_STEP(T.z, 6); HW_STEP(T.w, 7);

    // Forecast & loss term. s_idx = (511 + 12) % 24 = 19.
    const float f    = fmaf((float)HORIZON, b, L) * S[19];
    const float diff = f - yv;
    float val = diff * diff;

    // Wave (=block, 64 threads) reduction, one atomic per block.
    #pragma unroll
    for (int off = 32; off > 0; off >>= 1)
        val += __shfl_down(val, off);
    if (threadIdx.x == 0)
        atomicAdd(out, val);
}

extern "C" void kernel_launch(void* const* d_in, const int* in_sizes, int n_in,
                              void* d_out, int out_size, void* d_ws, size_t ws_size,
                              hipStream_t stream) {
    const float* x      = (const float*)d_in[0];
    const float* y      = (const float*)d_in[1];
    const float* init_L = (const float*)d_in[2];
    const float* init_b = (const float*)d_in[3];
    const float* init_S = (const float*)d_in[4];
    const float* alpha  = (const float*)d_in[5];
    const float* beta   = (const float*)d_in[6];
    const float* gamma  = (const float*)d_in[7];
    float* out = (float*)d_out;

    const int N = in_sizes[1];          // number of windows (32768)

    hipMemsetAsync(d_out, 0, (size_t)out_size * sizeof(float), stream);  // 0xAA-poisoned
    holtwinter_kernel<<<N / 64, 64, 0, stream>>>(
        x, y, init_L, init_b, init_S, alpha, beta, gamma, out);
}

// Round 9
// 115.948 us; speedup vs baseline: 1.1888x; 1.0481x over previous
//
#include <hip/hip_runtime.h>

// Holt-Winters triple exponential smoothing, 32768 windows x 511 steps.
// One thread per window (512 waves -> ~0.5 waves/SIMD: no TLP; all latency
// must be hidden by ILP). R8 post-mortem: source-ordered prefetch was
// dismantled by the scheduler (VGPR=96 proves buffers weren't co-live) ->
// this version PINS the pipeline with sched_barrier(0) fences and deepens
// it to 4 buffers / 3 blocks ahead (~1580 cyc cover vs ~900 cyc latency).
// Occupancy is structurally 2 waves/CU, so high VGPR use is free.

#define F_WINDOW 512
#define SEASONP  24
#define HORIZON  12

#define SBAR() __builtin_amdgcn_sched_barrier(0)

// One smoothing step. si MUST be a compile-time constant.
// u-form for bn: bn = (1-ab)*b - ab*L + ab*(xi-Sv)  (no dependence on Ln ->
// L and b chains are independent, 2 dependent FMAs each per step).
#define HW_STEP(xi, si) do {                       \
    const float Sv  = S[si];                       \
    const float d   = (xi) - Sv;                   \
    const float ad  = alpha * d;        /* a*d  */ \
    const float s_  = L + b;                       \
    const float Ln  = fmaf(oma, s_, ad);           \
    const float abd = beta * ad;        /* ab*d */ \
    const float tb  = fmaf(omab, b, abd);          \
    const float bn  = fmaf(ab, -L, tb);            \
    const float e   = (xi) - Ln;                   \
    const float gs  = omg * Sv;                    \
    S[si] = fmaf(gamma, e, gs);                    \
    L = Ln; b = bn;                                \
} while (0)

// 24 steps from six float4; entry step index i satisfies i % 24 == 4.
#define HW_BLOCK24(v0, v1, v2, v3, v4, v5) do {                                  \
    HW_STEP(v0.x,  4); HW_STEP(v0.y,  5); HW_STEP(v0.z,  6); HW_STEP(v0.w,  7); \
    HW_STEP(v1.x,  8); HW_STEP(v1.y,  9); HW_STEP(v1.z, 10); HW_STEP(v1.w, 11); \
    HW_STEP(v2.x, 12); HW_STEP(v2.y, 13); HW_STEP(v2.z, 14); HW_STEP(v2.w, 15); \
    HW_STEP(v3.x, 16); HW_STEP(v3.y, 17); HW_STEP(v3.z, 18); HW_STEP(v3.w, 19); \
    HW_STEP(v4.x, 20); HW_STEP(v4.y, 21); HW_STEP(v4.z, 22); HW_STEP(v4.w, 23); \
    HW_STEP(v5.x,  0); HW_STEP(v5.y,  1); HW_STEP(v5.z,  2); HW_STEP(v5.w,  3); \
} while (0)

// Issue six float4 loads into named buffer Bn0..Bn5 (stays in VGPRs).
#define LOAD6(Bn, base) do {                                \
    Bn##0 = *(const float4*)((base) +  0);                  \
    Bn##1 = *(const float4*)((base) +  4);                  \
    Bn##2 = *(const float4*)((base) +  8);                  \
    Bn##3 = *(const float4*)((base) + 12);                  \
    Bn##4 = *(const float4*)((base) + 16);                  \
    Bn##5 = *(const float4*)((base) + 20);                  \
} while (0)

__global__ __launch_bounds__(64) void holtwinter_kernel(
    const float* __restrict__ x,
    const float* __restrict__ y,
    const float* __restrict__ init_L,
    const float* __restrict__ init_b,
    const float* __restrict__ init_S,
    const float* __restrict__ p_alpha,
    const float* __restrict__ p_beta,
    const float* __restrict__ p_gamma,
    float* __restrict__ out)
{
    const int n = blockIdx.x * 64 + threadIdx.x;

    const float alpha = p_alpha[0];
    const float beta  = p_beta[0];
    const float gamma = p_gamma[0];
    const float oma   = 1.0f - alpha;
    const float ab    = alpha * beta;
    const float omab  = 1.0f - ab;
    const float omg   = 1.0f - gamma;

    const float* __restrict__ xr = x + (size_t)n * F_WINDOW;

    float4 A0, A1, A2, A3, A4, A5;      // pipeline buffers: 4 blocks deep
    float4 B0, B1, B2, B3, B4, B5;
    float4 C0, C1, C2, C3, C4, C5;
    float4 D0, D1, D2, D3, D4, D5;

    // ---- front of pipe: issue 3 blocks + all scalars, PINNED here ----
    LOAD6(A, xr + 4);                    // blk0: i = 4..27
    LOAD6(B, xr + 28);                   // blk1: i = 28..51
    LOAD6(C, xr + 52);                   // blk2: i = 52..75
    const float4 P = *(const float4*)(xr);        // i = 0..3 (x[0] unused)
    const float4 T = *(const float4*)(xr + 508);  // tail i = 508..511
    const float  yv = y[n];
    const float  L0 = init_L[n];
    const float  b0 = init_b[n];
    SBAR();

    // Seasonal state into registers (row is 96B-aligned: 96 = 6*16).
    float S[SEASONP];
    {
        const float4* iS4 = (const float4*)(init_S + (size_t)n * SEASONP);
        float4 s0 = iS4[0], s1 = iS4[1], s2 = iS4[2];
        float4 s3 = iS4[3], s4 = iS4[4], s5 = iS4[5];
        S[0]=s0.x;  S[1]=s0.y;  S[2]=s0.z;  S[3]=s0.w;
        S[4]=s1.x;  S[5]=s1.y;  S[6]=s1.z;  S[7]=s1.w;
        S[8]=s2.x;  S[9]=s2.y;  S[10]=s2.z; S[11]=s2.w;
        S[12]=s3.x; S[13]=s3.y; S[14]=s3.z; S[15]=s3.w;
        S[16]=s4.x; S[17]=s4.y; S[18]=s4.z; S[19]=s4.w;
        S[20]=s5.x; S[21]=s5.y; S[22]=s5.z; S[23]=s5.w;
    }

    float L = L0;
    float b = b0;

    // Prologue steps i = 1..3 (si = 1,2,3) — overlaps A/B/C flight time.
    HW_STEP(P.y, 1);
    HW_STEP(P.z, 2);
    HW_STEP(P.w, 3);
    SBAR();

    // 21 blocks of 24 steps (i = 4..507). Period-4 pipeline, 3 blocks in
    // flight past the one being computed. sched_barrier(0) fences forbid
    // the scheduler from sinking loads toward their uses (R8 failure).
    #pragma unroll 1
    for (int m = 0; m < 4; ++m) {
        const float* base = xr + 4 + 96 * m;
        LOAD6(D, base +  72); SBAR();              // blk 4m+3
        HW_BLOCK24(A0, A1, A2, A3, A4, A5); SBAR();// blk 4m
        LOAD6(A, base +  96); SBAR();              // blk 4m+4
        HW_BLOCK24(B0, B1, B2, B3, B4, B5); SBAR();// blk 4m+1
        LOAD6(B, base + 120); SBAR();              // blk 4m+5
        HW_BLOCK24(C0, C1, C2, C3, C4, C5); SBAR();// blk 4m+2
        LOAD6(C, base + 144); SBAR();              // blk 4m+6
        HW_BLOCK24(D0, D1, D2, D3, D4, D5); SBAR();// blk 4m+3
    }
    // After loop: A=blk16, B=blk17, C=blk18 loaded. Compute 16..20.
    LOAD6(D, xr + 460); SBAR();                    // blk19: i = 460..483
    HW_BLOCK24(A0, A1, A2, A3, A4, A5); SBAR();    // blk16
    LOAD6(A, xr + 484); SBAR();                    // blk20: i = 484..507
    HW_BLOCK24(B0, B1, B2, B3, B4, B5); SBAR();    // blk17
    HW_BLOCK24(C0, C1, C2, C3, C4, C5); SBAR();    // blk18
    HW_BLOCK24(D0, D1, D2, D3, D4, D5); SBAR();    // blk19
    HW_BLOCK24(A0, A1, A2, A3, A4, A5);            // blk20

    // Tail steps i = 508..511 (si = 4..7), loaded at kernel entry.
    HW_STEP(T.x, 4); HW_STEP(T.y, 5); HW_STEP(T.z, 6); HW_STEP(T.w, 7);

    // Forecast & loss term. s_idx = (511 + 12) % 24 = 19.
    const float f    = fmaf((float)HORIZON, b, L) * S[19];
    const float diff = f - yv;
    float val = diff * diff;

    // Wave (=block, 64 threads) reduction, one atomic per block.
    #pragma unroll
    for (int off = 32; off > 0; off >>= 1)
        val += __shfl_down(val, off);
    if (threadIdx.x == 0)
        atomicAdd(out, val);
}

extern "C" void kernel_launch(void* const* d_in, const int* in_sizes, int n_in,
                              void* d_out, int out_size, void* d_ws, size_t ws_size,
                              hipStream_t stream) {
    const float* x      = (const float*)d_in[0];
    const float* y      = (const float*)d_in[1];
    const float* init_L = (const float*)d_in[2];
    const float* init_b = (const float*)d_in[3];
    const float* init_S = (const float*)d_in[4];
    const float* alpha  = (const float*)d_in[5];
    const float* beta   = (const float*)d_in[6];
    const float* gamma  = (const float*)d_in[7];
    float* out = (float*)d_out;

    const int N = in_sizes[1];          // number of windows (32768)

    hipMemsetAsync(d_out, 0, (size_t)out_size * sizeof(float), stream);  // 0xAA-poisoned
    holtwinter_kernel<<<N / 64, 64, 0, stream>>>(
        x, y, init_L, init_b, init_S, alpha, beta, gamma, out);
}